// Round 1
// 1292.297 us; speedup vs baseline: 1.0933x; 1.0933x over previous
//
#include <hip/hip_runtime.h>

// Problem constants (fixed by setup_inputs)
constexpr int Bb = 16, Ll = 2048, Ee = 128, Hh = 256, Dd = 64, Kc = 512, Vv = 4096;
constexpr int NN = Bb * Ll;            // 32768 positions
constexpr int LOGITS = NN * Vv;        // 134217728

typedef __attribute__((ext_vector_type(8))) short bf16x8;   // 8 bf16 in 4 VGPRs
typedef __attribute__((ext_vector_type(4))) float f32x4;

// ---------------------------------------------------------------------------
// Weight transpose: w (Cout, Cin, KW) -> wt (KW, Cin, Cout) so GEMM B-tiles
// load coalesced.
__global__ void transpose_w(const float* __restrict__ w, float* __restrict__ wt,
                            int Cout, int Cin, int KW) {
    int i = blockIdx.x * 256 + threadIdx.x;
    int total = Cout * Cin * KW;
    if (i >= total) return;
    int co  = i / (Cin * KW);
    int rem = i - co * (Cin * KW);
    int ci  = rem / KW;
    int k   = rem - ci * KW;
    wt[((size_t)(k * Cin + ci)) * Cout + co] = w[i];
}

// ---------------------------------------------------------------------------
// Embedding gather: out[n, :] = token_emb[x[n], :]  (E=128 -> 32 float4/row)
__global__ void embed_kernel(const int* __restrict__ x,
                             const float4* __restrict__ te,
                             float4* __restrict__ out) {
    int gid = blockIdx.x * 256 + threadIdx.x;   // N*32 total
    int n = gid >> 5;
    int c = gid & 31;
    out[gid] = te[((size_t)x[n] << 5) + c];
}

// ---------------------------------------------------------------------------
// bf16x3 split: fp32 (M, K) row-major -> bf16 (M, 3K).
// LO_MID=true  : blocks [hi | lo | hi]  (activation pattern)
// LO_MID=false : blocks [hi | hi | lo]  (weight pattern)
// Sum over 3K of A'[hi|lo|hi] * W'[hi|hi|lo] = AhWh + AlWh + AhWl ~= A*W
// (error ~2^-18 relative per product).
__device__ __forceinline__ unsigned short f2bf_rne(float f) {
    unsigned int u = __float_as_uint(f);
    unsigned int r = (u + 0x7fffu + ((u >> 16) & 1u)) >> 16;
    return (unsigned short)r;
}
__device__ __forceinline__ float bf2f(unsigned short h) {
    return __uint_as_float((unsigned int)h << 16);
}

template <bool LO_MID>
__global__ void split3(const float* __restrict__ in, short* __restrict__ out, int K) {
    int idx = blockIdx.x * 256 + threadIdx.x;   // one per input element
    int m = idx / K;
    int k = idx - m * K;
    float a = in[idx];
    unsigned short hi = f2bf_rne(a);
    unsigned short lo = f2bf_rne(a - bf2f(hi));
    size_t base = (size_t)m * (3 * K) + k;
    out[base]         = (short)hi;
    out[base + K]     = (short)(LO_MID ? lo : hi);
    out[base + 2 * K] = (short)(LO_MID ? hi : lo);
}

// ---------------------------------------------------------------------------
// bf16 MFMA GEMM: Y(M,Nout) = A3(M,KK) * B3(Nout,KK)^T + bias.
// Both operands row-major, K-contiguous (B^T layout). 128x128 tile, BK=32,
// 4 waves in 2x2 grid, each wave 4x4 fragments of 16x16x32 MFMA.
// LDS layout per tile: [kb(0..3)][row(0..127)][8 bf16] so that fragment
// ds_read_b128 are bank-conflict-free (2-way only, which is free) and
// global_load_lds's linear "base + lane*16" dest matches.
__device__ __forceinline__ void gload16(const void* g, void* l) {
    __builtin_amdgcn_global_load_lds(
        (const __attribute__((address_space(1))) unsigned int*)g,
        (__attribute__((address_space(3))) unsigned int*)l, 16, 0, 0);
}

template <bool RELU>
__global__ __launch_bounds__(256) void gemm_mfma(
    const short* __restrict__ A3, const short* __restrict__ B3,
    const float* __restrict__ bias, float* __restrict__ Y,
    int KK, int Nout) {
    __shared__ short As[4096];   // 4 kb * 128 rows * 8 bf16 = 8 KB
    __shared__ short Bs[4096];

    const int tid  = threadIdx.x;
    const int lane = tid & 63;
    const int wid  = tid >> 6;
    const int ntile = Nout >> 7;
    const int tm = blockIdx.x / ntile;
    const int tn = blockIdx.x - tm * ntile;
    const int m0 = tm << 7;
    const int n0 = tn << 7;

    const int wm = wid >> 1, wn = wid & 1;     // wave 2x2 grid
    const int lr = lane & 15;                  // row/col within fragment
    const int kg = lane >> 4;                  // k-group (0..3) = kb

    f32x4 acc[4][4];
#pragma unroll
    for (int i = 0; i < 4; ++i)
#pragma unroll
        for (int j = 0; j < 4; ++j)
#pragma unroll
            for (int q = 0; q < 4; ++q) acc[i][j][q] = 0.f;

    const short* Ag = A3 + (size_t)m0 * KK;
    const short* Bg = B3 + (size_t)n0 * KK;

    for (int k0 = 0; k0 < KK; k0 += 32) {
        // ---- stage A tile: wave `wid` fills kb=wid, rows j*64+lane ----
#pragma unroll
        for (int j = 0; j < 2; ++j) {
            const short* g = Ag + (size_t)(j * 64 + lane) * KK + k0 + wid * 8;
            short* l = As + (size_t)(wid * 128 + j * 64) * 8;   // +lane*16B by HW
            gload16(g, l);
        }
        // ---- stage B tile ----
#pragma unroll
        for (int j = 0; j < 2; ++j) {
            const short* g = Bg + (size_t)(j * 64 + lane) * KK + k0 + wid * 8;
            short* l = Bs + (size_t)(wid * 128 + j * 64) * 8;
            gload16(g, l);
        }
        __syncthreads();   // compiler drains vmcnt here

        bf16x8 af[4], bfr[4];
#pragma unroll
        for (int i = 0; i < 4; ++i)
            af[i] = *reinterpret_cast<const bf16x8*>(
                &As[(size_t)(kg * 128 + wm * 64 + i * 16 + lr) * 8]);
#pragma unroll
        for (int j = 0; j < 4; ++j)
            bfr[j] = *reinterpret_cast<const bf16x8*>(
                &Bs[(size_t)(kg * 128 + wn * 64 + j * 16 + lr) * 8]);
#pragma unroll
        for (int i = 0; i < 4; ++i)
#pragma unroll
            for (int j = 0; j < 4; ++j)
                acc[i][j] = __builtin_amdgcn_mfma_f32_16x16x32_bf16(
                    af[i], bfr[j], acc[i][j], 0, 0, 0);
        __syncthreads();
    }

    // ---- epilogue: C/D layout col=lane&15, row=(lane>>4)*4+reg ----
#pragma unroll
    for (int i = 0; i < 4; ++i) {
        int r0 = m0 + wm * 64 + i * 16 + kg * 4;
#pragma unroll
        for (int j = 0; j < 4; ++j) {
            int col = n0 + wn * 64 + j * 16 + lr;
            float bv = bias[col];
#pragma unroll
            for (int q = 0; q < 4; ++q) {
                float v = acc[i][j][q] + bv;
                if (RELU) v = fmaxf(v, 0.f);
                Y[(size_t)(r0 + q) * Nout + col] = v;
            }
        }
    }
}

// ---------------------------------------------------------------------------
// Generic tiled GEMM / conv1d (cross-correlation, pad=(KW-1)/2). fp32 VALU.
// A: (N, Cin) activations. Wt: (KW, Cin, Cout). Y: (N, Cout).
template <int KW, bool RELU, int BM, int BN, int TM, int TN>
__global__ __launch_bounds__(256) void gemm_conv(
    const float* __restrict__ A, const float* __restrict__ Wt,
    const float* __restrict__ bias, float* __restrict__ Y, int Cin, int Cout) {
    constexpr int BK = 16;
    const int tid = threadIdx.x;
    const int tx = tid % (BN / TN);   // 16
    const int ty = tid / (BN / TN);   // 16
    const int n0  = blockIdx.x * BM;
    const int co0 = blockIdx.y * BN;

    __shared__ float As[BK][BM + 4];  // stored transposed: As[c][row]
    __shared__ float Bs[BK][BN];      // Bs[c][col]

    float acc[TM][TN];
#pragma unroll
    for (int i = 0; i < TM; i++)
#pragma unroll
        for (int j = 0; j < TN; j++) acc[i][j] = 0.f;

    constexpr int A4 = BM * BK / (256 * 4);
    constexpr int B4 = BN * BK / (256 * 4);

    for (int k = 0; k < KW; ++k) {
        const int shift = k - (KW - 1) / 2;
        for (int ci0 = 0; ci0 < Cin; ci0 += BK) {
            // ---- stage A tile (transposed into LDS) ----
#pragma unroll
            for (int v = 0; v < A4; ++v) {
                int f4 = v * 256 + tid;          // float4 slot
                int r  = f4 / (BK / 4);          // row in tile
                int c4 = f4 % (BK / 4);          // which float4 of the 16 ci
                int n = n0 + r;
                float4 val = make_float4(0.f, 0.f, 0.f, 0.f);
                if (KW == 1) {
                    val = *(const float4*)(A + (size_t)n * Cin + ci0 + c4 * 4);
                } else {
                    int l  = n & (Ll - 1);
                    int sl = l + shift;
                    if ((unsigned)sl < (unsigned)Ll)
                        val = *(const float4*)(A + (size_t)(n + shift) * Cin + ci0 + c4 * 4);
                }
                As[c4 * 4 + 0][r] = val.x;
                As[c4 * 4 + 1][r] = val.y;
                As[c4 * 4 + 2][r] = val.z;
                As[c4 * 4 + 3][r] = val.w;
            }
            // ---- stage B tile ----
#pragma unroll
            for (int v = 0; v < B4; ++v) {
                int f4 = v * 256 + tid;
                int c  = f4 / (BN / 4);
                int j4 = f4 % (BN / 4);
                float4 w4 = *(const float4*)(Wt + (size_t)(k * Cin + ci0 + c) * Cout + co0 + j4 * 4);
                *(float4*)(&Bs[c][j4 * 4]) = w4;
            }
            __syncthreads();
            // ---- compute ----
#pragma unroll
            for (int cc = 0; cc < BK; ++cc) {
                float a[TM], b[TN];
#pragma unroll
                for (int i = 0; i < TM; i += 4)
                    *(float4*)(&a[i]) = *(const float4*)(&As[cc][ty * TM + i]);
#pragma unroll
                for (int j = 0; j < TN; j += 4)
                    *(float4*)(&b[j]) = *(const float4*)(&Bs[cc][tx * TN + j]);
#pragma unroll
                for (int i = 0; i < TM; i++)
#pragma unroll
                    for (int j = 0; j < TN; j++)
                        acc[i][j] = fmaf(a[i], b[j], acc[i][j]);
            }
            __syncthreads();
        }
    }
    // ---- epilogue: bias (+relu), coalesced float4 stores ----
#pragma unroll
    for (int i = 0; i < TM; i++) {
        int n = n0 + ty * TM + i;
#pragma unroll
        for (int j = 0; j < TN; j += 4) {
            int co = co0 + tx * TN + j;
            float4 r;
            r.x = acc[i][j + 0] + bias[co + 0];
            r.y = acc[i][j + 1] + bias[co + 1];
            r.z = acc[i][j + 2] + bias[co + 2];
            r.w = acc[i][j + 3] + bias[co + 3];
            if (RELU) {
                r.x = fmaxf(r.x, 0.f); r.y = fmaxf(r.y, 0.f);
                r.z = fmaxf(r.z, 0.f); r.w = fmaxf(r.w, 0.f);
            }
            *(float4*)(Y + (size_t)n * Cout + co) = r;
        }
    }
}

// ---------------------------------------------------------------------------
// VQ argmin: per block, 64 rows vs all 512 codes (chunks of 64), D=64.
// dist = sum_d (z-c)^2 ; tie-break = lowest code index (np.argmin semantics).
__global__ __launch_bounds__(256) void vq_kernel(
    const float* __restrict__ ze, const float* __restrict__ cb,
    int* __restrict__ codes_i, float* __restrict__ codes_f) {
    const int tid = threadIdx.x;
    const int tx = tid & 15, ty = tid >> 4;
    const int n0 = blockIdx.x * 64;

    __shared__ float Zs[Dd][64 + 4];   // [d][row]
    __shared__ float Cs[Dd][64 + 4];   // [d][code]
    __shared__ float bD[64][17];
    __shared__ int   bI[64][17];

    // stage z rows (transposed)
#pragma unroll
    for (int v = 0; v < 4; ++v) {
        int f4 = v * 256 + tid;       // 1024 float4
        int row = f4 >> 4, d4 = f4 & 15;
        float4 z = *(const float4*)(ze + (size_t)(n0 + row) * Dd + d4 * 4);
        Zs[d4 * 4 + 0][row] = z.x;
        Zs[d4 * 4 + 1][row] = z.y;
        Zs[d4 * 4 + 2][row] = z.z;
        Zs[d4 * 4 + 3][row] = z.w;
    }

    float best[4];
    int   bidx[4];
#pragma unroll
    for (int i = 0; i < 4; i++) { best[i] = 3.4e38f; bidx[i] = 0; }

    for (int ch = 0; ch < Kc / 64; ++ch) {
        int c0 = ch * 64;
        __syncthreads();
#pragma unroll
        for (int v = 0; v < 4; ++v) {
            int f4 = v * 256 + tid;
            int j = f4 >> 4, d4 = f4 & 15;
            float4 w = *(const float4*)(cb + (size_t)(c0 + j) * Dd + d4 * 4);
            Cs[d4 * 4 + 0][j] = w.x;
            Cs[d4 * 4 + 1][j] = w.y;
            Cs[d4 * 4 + 2][j] = w.z;
            Cs[d4 * 4 + 3][j] = w.w;
        }
        __syncthreads();

        float dist[4][4];
#pragma unroll
        for (int i = 0; i < 4; i++)
#pragma unroll
            for (int j = 0; j < 4; j++) dist[i][j] = 0.f;

#pragma unroll 8
        for (int d = 0; d < Dd; ++d) {
            float a[4], b[4];
            *(float4*)a = *(const float4*)(&Zs[d][ty * 4]);
            *(float4*)b = *(const float4*)(&Cs[d][tx * 4]);
#pragma unroll
            for (int i = 0; i < 4; i++)
#pragma unroll
                for (int j = 0; j < 4; j++) {
                    float df = a[i] - b[j];
                    dist[i][j] = fmaf(df, df, dist[i][j]);
                }
        }
#pragma unroll
        for (int i = 0; i < 4; i++)
#pragma unroll
            for (int j = 0; j < 4; j++) {
                int ci = c0 + tx * 4 + j;
                if (dist[i][j] < best[i]) { best[i] = dist[i][j]; bidx[i] = ci; }
            }
    }
    __syncthreads();
#pragma unroll
    for (int i = 0; i < 4; i++) {
        bD[ty * 4 + i][tx] = best[i];
        bI[ty * 4 + i][tx] = bidx[i];
    }
    __syncthreads();
    if (tid < 64) {
        float bd = bD[tid][0];
        int   bi = bI[tid][0];
        for (int t = 1; t < 16; ++t) {
            float d = bD[tid][t];
            int   ix = bI[tid][t];
            if (d < bd || (d == bd && ix < bi)) { bd = d; bi = ix; }
        }
        codes_i[n0 + tid] = bi;
        codes_f[n0 + tid] = (float)bi;
    }
}

// ---------------------------------------------------------------------------
// z_q gather: zq[n,:] = codebook[codes[n],:]  (D=64 -> 16 float4/row)
__global__ void gather_zq(const int* __restrict__ codes,
                          const float4* __restrict__ cb, float4* __restrict__ zq) {
    int gid = blockIdx.x * 256 + threadIdx.x;  // N*16
    int n = gid >> 4, c = gid & 15;
    zq[gid] = cb[((size_t)codes[n] << 4) + c];
}

// ---------------------------------------------------------------------------
// Commitment loss, two-stage deterministic reduction.
__global__ __launch_bounds__(256) void commit_partial(
    const float* __restrict__ ze, const float* __restrict__ zq,
    float* __restrict__ partial) {
    float s = 0.f;
    for (int i = blockIdx.x * 256 + threadIdx.x; i < NN * Dd; i += 1024 * 256) {
        float d = ze[i] - zq[i];
        s = fmaf(d, d, s);
    }
    for (int off = 32; off; off >>= 1) s += __shfl_down(s, off, 64);
    __shared__ float w[4];
    int lane = threadIdx.x & 63, wv = threadIdx.x >> 6;
    if (lane == 0) w[wv] = s;
    __syncthreads();
    if (threadIdx.x == 0) partial[blockIdx.x] = w[0] + w[1] + w[2] + w[3];
}

__global__ void commit_final(const float* __restrict__ partial, float* __restrict__ loss) {
    float s = 0.f;
    for (int i = threadIdx.x; i < 1024; i += 256) s += partial[i];
    for (int off = 32; off; off >>= 1) s += __shfl_down(s, off, 64);
    __shared__ float w[4];
    int lane = threadIdx.x & 63, wv = threadIdx.x >> 6;
    if (lane == 0) w[wv] = s;
    __syncthreads();
    if (threadIdx.x == 0)
        loss[0] = 0.1f * (w[0] + w[1] + w[2] + w[3]) / (float)(NN * Dd);
}

// ---------------------------------------------------------------------------
extern "C" void kernel_launch(void* const* d_in, const int* in_sizes, int n_in,
                              void* d_out, int out_size, void* d_ws, size_t ws_size,
                              hipStream_t stream) {
    const int*   x    = (const int*)d_in[0];
    const float* te   = (const float*)d_in[1];
    const float* ew1  = (const float*)d_in[2];
    const float* eb1  = (const float*)d_in[3];
    const float* ew2  = (const float*)d_in[4];
    const float* eb2  = (const float*)d_in[5];
    const float* ew3  = (const float*)d_in[6];
    const float* eb3  = (const float*)d_in[7];
    const float* cb   = (const float*)d_in[8];
    const float* dw1  = (const float*)d_in[9];
    const float* db1  = (const float*)d_in[10];
    const float* dw2  = (const float*)d_in[11];
    const float* db2  = (const float*)d_in[12];
    const float* dw3  = (const float*)d_in[13];
    const float* db3  = (const float*)d_in[14];
    const float* outw = (const float*)d_in[15];
    const float* outb = (const float*)d_in[16];

    char* ws = (char*)d_ws;
    size_t off = 0;
    auto alloc = [&](size_t bytes) -> void* {
        void* p = ws + off;
        off = (off + bytes + 255) & ~(size_t)255;
        return p;
    };
    float* bufA   = (float*)alloc((size_t)NN * Ee * 4);  // emb / hd3
    float* bufB   = (float*)alloc((size_t)NN * Hh * 4);  // h1 / hd1
    float* bufC   = (float*)alloc((size_t)NN * Hh * 4);  // h2 / hd2
    float* bufZ   = (float*)alloc((size_t)NN * Dd * 4);  // z_e
    float* bufQ   = (float*)alloc((size_t)NN * Dd * 4);  // z_q
    int*   codesi = (int*)alloc((size_t)NN * 4);
    float* part   = (float*)alloc(1024 * 4);
    float* wt_e1  = (float*)alloc((size_t)3 * Ee * Hh * 4);
    float* wt_e2  = (float*)alloc((size_t)3 * Hh * Hh * 4);
    float* wt_e3  = (float*)alloc((size_t)Hh * Dd * 4);
    float* wt_d1  = (float*)alloc((size_t)Dd * Hh * 4);
    float* wt_d2  = (float*)alloc((size_t)3 * Hh * Hh * 4);
    float* wt_d3  = (float*)alloc((size_t)Hh * Ee * 4);
    short* a3     = (short*)alloc((size_t)NN * 3 * Ee * 2);  // bf16x3 activations
    short* w3     = (short*)alloc((size_t)Vv * 3 * Ee * 2);  // bf16x3 out_w

    float* out       = (float*)d_out;
    float* out_loss  = out + (size_t)LOGITS;
    float* out_codes = out_loss + 1;

    auto tg = [](int n) { return dim3((n + 255) / 256); };
    transpose_w<<<tg(Hh * Ee * 3), 256, 0, stream>>>(ew1, wt_e1, Hh, Ee, 3);
    transpose_w<<<tg(Hh * Hh * 3), 256, 0, stream>>>(ew2, wt_e2, Hh, Hh, 3);
    transpose_w<<<tg(Dd * Hh),     256, 0, stream>>>(ew3, wt_e3, Dd, Hh, 1);
    transpose_w<<<tg(Hh * Dd),     256, 0, stream>>>(dw1, wt_d1, Hh, Dd, 1);
    transpose_w<<<tg(Hh * Hh * 3), 256, 0, stream>>>(dw2, wt_d2, Hh, Hh, 3);
    transpose_w<<<tg(Ee * Hh),     256, 0, stream>>>(dw3, wt_d3, Ee, Hh, 1);
    // out_w (V, E) row-major is already the B^T layout gemm_mfma wants:
    // split-convert it to bf16x3 [hi | hi | lo].
    split3<false><<<tg(Vv * Ee), 256, 0, stream>>>(outw, w3, Ee);

    embed_kernel<<<dim3(NN * 32 / 256), 256, 0, stream>>>(x, (const float4*)te, (float4*)bufA);

    // Encoder (fp32 to keep VQ argmin exact — do NOT lower precision here:
    // argmin tie margins are ~1e-3 and bf16x3's ~1e-5 z_e error flips codes)
    gemm_conv<3, true, 128, 128, 8, 8><<<dim3(NN / 128, Hh / 128), 256, 0, stream>>>(bufA, wt_e1, eb1, bufB, Ee, Hh);
    gemm_conv<3, true, 128, 128, 8, 8><<<dim3(NN / 128, Hh / 128), 256, 0, stream>>>(bufB, wt_e2, eb2, bufC, Hh, Hh);
    gemm_conv<1, false, 64, 64, 4, 4><<<dim3(NN / 64, 1), 256, 0, stream>>>(bufC, wt_e3, eb3, bufZ, Hh, Dd);

    // VQ
    vq_kernel<<<dim3(NN / 64), 256, 0, stream>>>(bufZ, cb, codesi, out_codes);
    gather_zq<<<dim3(NN * 16 / 256), 256, 0, stream>>>(codesi, (const float4*)cb, (float4*)bufQ);
    commit_partial<<<dim3(1024), 256, 0, stream>>>(bufZ, bufQ, part);
    commit_final<<<dim3(1), 256, 0, stream>>>(part, out_loss);

    // Decoder (fp32 — decoder input z_q is exact, candidates for later rounds)
    gemm_conv<1, true, 128, 128, 8, 8><<<dim3(NN / 128, Hh / 128), 256, 0, stream>>>(bufQ, wt_d1, db1, bufB, Dd, Hh);
    gemm_conv<3, true, 128, 128, 8, 8><<<dim3(NN / 128, Hh / 128), 256, 0, stream>>>(bufB, wt_d2, db2, bufC, Hh, Hh);
    gemm_conv<1, true, 128, 128, 8, 8><<<dim3(NN / 128, Ee / 128), 256, 0, stream>>>(bufC, wt_d3, db3, bufA, Hh, Ee);

    // Vocab projection -> logits via bf16x3 MFMA:
    // A' = [Ah | Al | Ah] (NN, 384), W' = [Wh | Wh | Wl] (V, 384),
    // one bf16 GEMM with K'=384 computes AhWh + AlWh + AhWl (~fp32 accurate).
    split3<true><<<tg(NN * Ee), 256, 0, stream>>>(bufA, a3, Ee);
    gemm_mfma<false><<<dim3((NN / 128) * (Vv / 128)), 256, 0, stream>>>(
        a3, w3, outb, out, 3 * Ee, Vv);
}

// Round 2
// 1223.899 us; speedup vs baseline: 1.1544x; 1.0559x over previous
//
#include <hip/hip_runtime.h>

// Problem constants (fixed by setup_inputs)
constexpr int Bb = 16, Ll = 2048, Ee = 128, Hh = 256, Dd = 64, Kc = 512, Vv = 4096;
constexpr int NN = Bb * Ll;            // 32768 positions
constexpr int LOGITS = NN * Vv;        // 134217728

typedef __attribute__((ext_vector_type(8))) short bf16x8;   // 8 bf16 in 4 VGPRs
typedef __attribute__((ext_vector_type(4))) float f32x4;

// ---------------------------------------------------------------------------
// Weight transpose (encoder fp32 path): w (Cout, Cin, KW) -> wt (KW, Cin, Cout)
__global__ void transpose_w(const float* __restrict__ w, float* __restrict__ wt,
                            int Cout, int Cin, int KW) {
    int i = blockIdx.x * 256 + threadIdx.x;
    int total = Cout * Cin * KW;
    if (i >= total) return;
    int co  = i / (Cin * KW);
    int rem = i - co * (Cin * KW);
    int ci  = rem / KW;
    int k   = rem - ci * KW;
    wt[((size_t)(k * Cin + ci)) * Cout + co] = w[i];
}

// ---------------------------------------------------------------------------
// Embedding gather: out[n, :] = token_emb[x[n], :]  (E=128 -> 32 float4/row)
__global__ void embed_kernel(const int* __restrict__ x,
                             const float4* __restrict__ te,
                             float4* __restrict__ out) {
    int gid = blockIdx.x * 256 + threadIdx.x;   // N*32 total
    int n = gid >> 5;
    int c = gid & 31;
    out[gid] = te[((size_t)x[n] << 5) + c];
}

// ---------------------------------------------------------------------------
// bf16x3 split helpers.
// Activation pattern: [hi | lo | hi]   Weight pattern: [hi | hi | lo]
// Sum over 3K of A'[hi|lo|hi] * W'[hi|hi|lo] = AhWh + AlWh + AhWl ~= A*W
// (error ~2^-17 relative per product).
__device__ __forceinline__ unsigned short f2bf_rne(float f) {
    unsigned int u = __float_as_uint(f);
    unsigned int r = (u + 0x7fffu + ((u >> 16) & 1u)) >> 16;
    return (unsigned short)r;
}
__device__ __forceinline__ float bf2f(unsigned short h) {
    return __uint_as_float((unsigned int)h << 16);
}

template <bool LO_MID>   // true: [hi|lo|hi] (activations), false: [hi|hi|lo] (weights)
__global__ void split3(const float* __restrict__ in, short* __restrict__ out, int K) {
    int idx = blockIdx.x * 256 + threadIdx.x;   // one per input element
    int m = idx / K;
    int k = idx - m * K;
    float a = in[idx];
    unsigned short hi = f2bf_rne(a);
    unsigned short lo = f2bf_rne(a - bf2f(hi));
    size_t base = (size_t)m * (3 * K) + k;
    out[base]         = (short)hi;
    out[base + K]     = (short)(LO_MID ? lo : hi);
    out[base + 2 * K] = (short)(LO_MID ? hi : lo);
}

// Conv weight (Cout, Cin, 3) -> w3 (Cout, 3 taps, [hi|hi|lo]*Cin)
__global__ void split3_w3(const float* __restrict__ w, short* __restrict__ w3,
                          int Cout, int Cin) {
    int idx = blockIdx.x * 256 + threadIdx.x;   // Cout*Cin*3
    int total = Cout * Cin * 3;
    if (idx >= total) return;
    int co  = idx / (Cin * 3);
    int rem = idx - co * (Cin * 3);
    int ci  = rem / 3;
    int k   = rem - ci * 3;
    float a = w[idx];
    unsigned short hi = f2bf_rne(a);
    unsigned short lo = f2bf_rne(a - bf2f(hi));
    size_t base = (size_t)co * (9 * Cin) + (size_t)k * (3 * Cin) + ci;
    w3[base]            = (short)hi;
    w3[base + Cin]      = (short)hi;
    w3[base + 2 * Cin]  = (short)lo;
}

// Zero the guard rows (row index NN) of the bf16x3 activation buffers, so
// KW=3 boundary taps read zeros via global_load_lds (which can't lane-mask).
__global__ void zero_guards(short* __restrict__ q3, short* __restrict__ h1,
                            short* __restrict__ h2, short* __restrict__ h3) {
    int t = threadIdx.x;
    for (int i = t; i < 192; i += 256) q3[(size_t)NN * 192 + i] = 0;
    for (int i = t; i < 768; i += 256) h1[(size_t)NN * 768 + i] = 0;
    for (int i = t; i < 768; i += 256) h2[(size_t)NN * 768 + i] = 0;
    for (int i = t; i < 384; i += 256) h3[(size_t)NN * 384 + i] = 0;
}

// ---------------------------------------------------------------------------
// bf16 MFMA GEMM / conv1d: Y(M,Nout) = sum_taps A3(M,KK)*B3(Nout,KW*KK)^T + bias.
// A3 row-major (NN+1 rows, guard row NN zeroed), K-contiguous per tap.
// 128x128 tile, BK=32, 4 waves (2x2), each wave 4x4 frags of 16x16x32 MFMA.
// LDS: [kb(0..3)][row(0..127)][8 bf16] -> ds_read_b128 only free 2-way
// conflicts; matches global_load_lds linear "base + lane*16" dest.
// OUT3: epilogue emits the NEXT layer's bf16x3 activation operand [hi|lo|hi].
__device__ __forceinline__ void gload16(const void* g, void* l) {
    __builtin_amdgcn_global_load_lds(
        (const __attribute__((address_space(1))) unsigned int*)g,
        (__attribute__((address_space(3))) unsigned int*)l, 16, 0, 0);
}

template <int KW, bool RELU, bool OUT3>
__global__ __launch_bounds__(256) void gemm_mfma(
    const short* __restrict__ A3, const short* __restrict__ B3,
    const float* __restrict__ bias, float* __restrict__ Yf,
    short* __restrict__ Y3, int KK, int Nout) {
    __shared__ short As[4096];   // 4 kb * 128 rows * 8 bf16 = 8 KB
    __shared__ short Bs[4096];

    const int tid  = threadIdx.x;
    const int lane = tid & 63;
    const int wid  = tid >> 6;

    // bijective XCD swizzle (all grids used are divisible by 8)
    const int nwg = gridDim.x;
    const int bid = blockIdx.x;
    const int swz = (bid & 7) * (nwg >> 3) + (bid >> 3);

    const int ntile = Nout >> 7;
    const int tm = swz / ntile;
    const int tn = swz - tm * ntile;
    const int m0 = tm << 7;
    const int n0 = tn << 7;

    const int wm = wid >> 1, wn = wid & 1;     // wave 2x2 grid
    const int lr = lane & 15;                  // row/col within fragment
    const int kg = lane >> 4;                  // k-group (0..3)

    f32x4 acc[4][4];
#pragma unroll
    for (int i = 0; i < 4; ++i)
#pragma unroll
        for (int j = 0; j < 4; ++j)
#pragma unroll
            for (int q = 0; q < 4; ++q) acc[i][j][q] = 0.f;

    const int BKW = KW * KK;   // B3 row length

    for (int kt = 0; kt < KW; ++kt) {
        const int shift = kt - (KW - 1) / 2;
        for (int k0 = 0; k0 < KK; k0 += 32) {
            // ---- stage A tile: wave `wid` fills kb=wid, rows j*64+lane ----
#pragma unroll
            for (int j = 0; j < 2; ++j) {
                int r = m0 + j * 64 + lane;
                int src = r;
                if (KW > 1) {
                    int sl = (r & (Ll - 1)) + shift;
                    src = ((unsigned)sl < (unsigned)Ll) ? r + shift : NN;  // guard
                }
                const short* g = A3 + (size_t)src * KK + k0 + wid * 8;
                short* l = As + (size_t)(wid * 128 + j * 64) * 8;  // +lane*16B by HW
                gload16(g, l);
            }
            // ---- stage B tile ----
#pragma unroll
            for (int j = 0; j < 2; ++j) {
                const short* g = B3 + (size_t)(n0 + j * 64 + lane) * BKW
                                 + kt * KK + k0 + wid * 8;
                short* l = Bs + (size_t)(wid * 128 + j * 64) * 8;
                gload16(g, l);
            }
            __syncthreads();   // compiler drains vmcnt here

            bf16x8 af[4], bfr[4];
#pragma unroll
            for (int i = 0; i < 4; ++i)
                af[i] = *reinterpret_cast<const bf16x8*>(
                    &As[(size_t)(kg * 128 + wm * 64 + i * 16 + lr) * 8]);
#pragma unroll
            for (int j = 0; j < 4; ++j)
                bfr[j] = *reinterpret_cast<const bf16x8*>(
                    &Bs[(size_t)(kg * 128 + wn * 64 + j * 16 + lr) * 8]);
#pragma unroll
            for (int i = 0; i < 4; ++i)
#pragma unroll
                for (int j = 0; j < 4; ++j)
                    acc[i][j] = __builtin_amdgcn_mfma_f32_16x16x32_bf16(
                        af[i], bfr[j], acc[i][j], 0, 0, 0);
            __syncthreads();
        }
    }

    // ---- epilogue: C/D layout col=lane&15, row=(lane>>4)*4+reg ----
#pragma unroll
    for (int i = 0; i < 4; ++i) {
        int r0 = m0 + wm * 64 + i * 16 + kg * 4;
#pragma unroll
        for (int j = 0; j < 4; ++j) {
            int col = n0 + wn * 64 + j * 16 + lr;
            float bv = bias[col];
#pragma unroll
            for (int q = 0; q < 4; ++q) {
                float v = acc[i][j][q] + bv;
                if (RELU) v = fmaxf(v, 0.f);
                if (OUT3) {
                    unsigned short hi = f2bf_rne(v);
                    unsigned short lo = f2bf_rne(v - bf2f(hi));
                    size_t rb = (size_t)(r0 + q) * (3 * Nout);
                    Y3[rb + col]            = (short)hi;
                    Y3[rb + Nout + col]     = (short)lo;
                    Y3[rb + 2 * Nout + col] = (short)hi;
                } else {
                    Yf[(size_t)(r0 + q) * Nout + col] = v;
                }
            }
        }
    }
}

// ---------------------------------------------------------------------------
// Generic tiled GEMM / conv1d (cross-correlation, pad=(KW-1)/2). fp32 VALU.
// Encoder only: keeps z_e bit-identical so VQ argmin codes are exact.
template <int KW, bool RELU, int BM, int BN, int TM, int TN>
__global__ __launch_bounds__(256) void gemm_conv(
    const float* __restrict__ A, const float* __restrict__ Wt,
    const float* __restrict__ bias, float* __restrict__ Y, int Cin, int Cout) {
    constexpr int BK = 16;
    const int tid = threadIdx.x;
    const int tx = tid % (BN / TN);   // 16
    const int ty = tid / (BN / TN);   // 16
    const int n0  = blockIdx.x * BM;
    const int co0 = blockIdx.y * BN;

    __shared__ float As[BK][BM + 4];  // stored transposed: As[c][row]
    __shared__ float Bs[BK][BN];      // Bs[c][col]

    float acc[TM][TN];
#pragma unroll
    for (int i = 0; i < TM; i++)
#pragma unroll
        for (int j = 0; j < TN; j++) acc[i][j] = 0.f;

    constexpr int A4 = BM * BK / (256 * 4);
    constexpr int B4 = BN * BK / (256 * 4);

    for (int k = 0; k < KW; ++k) {
        const int shift = k - (KW - 1) / 2;
        for (int ci0 = 0; ci0 < Cin; ci0 += BK) {
            // ---- stage A tile (transposed into LDS) ----
#pragma unroll
            for (int v = 0; v < A4; ++v) {
                int f4 = v * 256 + tid;          // float4 slot
                int r  = f4 / (BK / 4);          // row in tile
                int c4 = f4 % (BK / 4);          // which float4 of the 16 ci
                int n = n0 + r;
                float4 val = make_float4(0.f, 0.f, 0.f, 0.f);
                if (KW == 1) {
                    val = *(const float4*)(A + (size_t)n * Cin + ci0 + c4 * 4);
                } else {
                    int l  = n & (Ll - 1);
                    int sl = l + shift;
                    if ((unsigned)sl < (unsigned)Ll)
                        val = *(const float4*)(A + (size_t)(n + shift) * Cin + ci0 + c4 * 4);
                }
                As[c4 * 4 + 0][r] = val.x;
                As[c4 * 4 + 1][r] = val.y;
                As[c4 * 4 + 2][r] = val.z;
                As[c4 * 4 + 3][r] = val.w;
            }
            // ---- stage B tile ----
#pragma unroll
            for (int v = 0; v < B4; ++v) {
                int f4 = v * 256 + tid;
                int c  = f4 / (BN / 4);
                int j4 = f4 % (BN / 4);
                float4 w4 = *(const float4*)(Wt + (size_t)(k * Cin + ci0 + c) * Cout + co0 + j4 * 4);
                *(float4*)(&Bs[c][j4 * 4]) = w4;
            }
            __syncthreads();
            // ---- compute ----
#pragma unroll
            for (int cc = 0; cc < BK; ++cc) {
                float a[TM], b[TN];
#pragma unroll
                for (int i = 0; i < TM; i += 4)
                    *(float4*)(&a[i]) = *(const float4*)(&As[cc][ty * TM + i]);
#pragma unroll
                for (int j = 0; j < TN; j += 4)
                    *(float4*)(&b[j]) = *(const float4*)(&Bs[cc][tx * TN + j]);
#pragma unroll
                for (int i = 0; i < TM; i++)
#pragma unroll
                    for (int j = 0; j < TN; j++)
                        acc[i][j] = fmaf(a[i], b[j], acc[i][j]);
            }
            __syncthreads();
        }
    }
    // ---- epilogue: bias (+relu), coalesced float4 stores ----
#pragma unroll
    for (int i = 0; i < TM; i++) {
        int n = n0 + ty * TM + i;
#pragma unroll
        for (int j = 0; j < TN; j += 4) {
            int co = co0 + tx * TN + j;
            float4 r;
            r.x = acc[i][j + 0] + bias[co + 0];
            r.y = acc[i][j + 1] + bias[co + 1];
            r.z = acc[i][j + 2] + bias[co + 2];
            r.w = acc[i][j + 3] + bias[co + 3];
            if (RELU) {
                r.x = fmaxf(r.x, 0.f); r.y = fmaxf(r.y, 0.f);
                r.z = fmaxf(r.z, 0.f); r.w = fmaxf(r.w, 0.f);
            }
            *(float4*)(Y + (size_t)n * Cout + co) = r;
        }
    }
}

// ---------------------------------------------------------------------------
// VQ argmin: per block, 64 rows vs all 512 codes (chunks of 64), D=64.
__global__ __launch_bounds__(256) void vq_kernel(
    const float* __restrict__ ze, const float* __restrict__ cb,
    int* __restrict__ codes_i, float* __restrict__ codes_f) {
    const int tid = threadIdx.x;
    const int tx = tid & 15, ty = tid >> 4;
    const int n0 = blockIdx.x * 64;

    __shared__ float Zs[Dd][64 + 4];   // [d][row]
    __shared__ float Cs[Dd][64 + 4];   // [d][code]
    __shared__ float bD[64][17];
    __shared__ int   bI[64][17];

    // stage z rows (transposed)
#pragma unroll
    for (int v = 0; v < 4; ++v) {
        int f4 = v * 256 + tid;       // 1024 float4
        int row = f4 >> 4, d4 = f4 & 15;
        float4 z = *(const float4*)(ze + (size_t)(n0 + row) * Dd + d4 * 4);
        Zs[d4 * 4 + 0][row] = z.x;
        Zs[d4 * 4 + 1][row] = z.y;
        Zs[d4 * 4 + 2][row] = z.z;
        Zs[d4 * 4 + 3][row] = z.w;
    }

    float best[4];
    int   bidx[4];
#pragma unroll
    for (int i = 0; i < 4; i++) { best[i] = 3.4e38f; bidx[i] = 0; }

    for (int ch = 0; ch < Kc / 64; ++ch) {
        int c0 = ch * 64;
        __syncthreads();
#pragma unroll
        for (int v = 0; v < 4; ++v) {
            int f4 = v * 256 + tid;
            int j = f4 >> 4, d4 = f4 & 15;
            float4 w = *(const float4*)(cb + (size_t)(c0 + j) * Dd + d4 * 4);
            Cs[d4 * 4 + 0][j] = w.x;
            Cs[d4 * 4 + 1][j] = w.y;
            Cs[d4 * 4 + 2][j] = w.z;
            Cs[d4 * 4 + 3][j] = w.w;
        }
        __syncthreads();

        float dist[4][4];
#pragma unroll
        for (int i = 0; i < 4; i++)
#pragma unroll
            for (int j = 0; j < 4; j++) dist[i][j] = 0.f;

#pragma unroll 8
        for (int d = 0; d < Dd; ++d) {
            float a[4], b[4];
            *(float4*)a = *(const float4*)(&Zs[d][ty * 4]);
            *(float4*)b = *(const float4*)(&Cs[d][tx * 4]);
#pragma unroll
            for (int i = 0; i < 4; i++)
#pragma unroll
                for (int j = 0; j < 4; j++) {
                    float df = a[i] - b[j];
                    dist[i][j] = fmaf(df, df, dist[i][j]);
                }
        }
#pragma unroll
        for (int i = 0; i < 4; i++)
#pragma unroll
            for (int j = 0; j < 4; j++) {
                int ci = c0 + tx * 4 + j;
                if (dist[i][j] < best[i]) { best[i] = dist[i][j]; bidx[i] = ci; }
            }
    }
    __syncthreads();
#pragma unroll
    for (int i = 0; i < 4; i++) {
        bD[ty * 4 + i][tx] = best[i];
        bI[ty * 4 + i][tx] = bidx[i];
    }
    __syncthreads();
    if (tid < 64) {
        float bd = bD[tid][0];
        int   bi = bI[tid][0];
        for (int t = 1; t < 16; ++t) {
            float d = bD[tid][t];
            int   ix = bI[tid][t];
            if (d < bd || (d == bd && ix < bi)) { bd = d; bi = ix; }
        }
        codes_i[n0 + tid] = bi;
        codes_f[n0 + tid] = (float)bi;
    }
}

// ---------------------------------------------------------------------------
// z_q gather (fp32, for commit loss): zq[n,:] = codebook[codes[n],:]
__global__ void gather_zq(const int* __restrict__ codes,
                          const float4* __restrict__ cb, float4* __restrict__ zq) {
    int gid = blockIdx.x * 256 + threadIdx.x;  // N*16
    int n = gid >> 4, c = gid & 15;
    zq[gid] = cb[((size_t)codes[n] << 4) + c];
}

// z_q gather (bf16x3, decoder operand): q3[n,:] = cb3[codes[n],:] (24 float4/row)
__global__ void gather_q3(const int* __restrict__ codes,
                          const float4* __restrict__ cb3, float4* __restrict__ q3) {
    int gid = blockIdx.x * 256 + threadIdx.x;  // N*24
    int n = gid / 24, c = gid - n * 24;
    q3[(size_t)n * 24 + c] = cb3[(size_t)codes[n] * 24 + c];
}

// ---------------------------------------------------------------------------
// Commitment loss, two-stage deterministic reduction.
__global__ __launch_bounds__(256) void commit_partial(
    const float* __restrict__ ze, const float* __restrict__ zq,
    float* __restrict__ partial) {
    float s = 0.f;
    for (int i = blockIdx.x * 256 + threadIdx.x; i < NN * Dd; i += 1024 * 256) {
        float d = ze[i] - zq[i];
        s = fmaf(d, d, s);
    }
    for (int off = 32; off; off >>= 1) s += __shfl_down(s, off, 64);
    __shared__ float w[4];
    int lane = threadIdx.x & 63, wv = threadIdx.x >> 6;
    if (lane == 0) w[wv] = s;
    __syncthreads();
    if (threadIdx.x == 0) partial[blockIdx.x] = w[0] + w[1] + w[2] + w[3];
}

__global__ void commit_final(const float* __restrict__ partial, float* __restrict__ loss) {
    float s = 0.f;
    for (int i = threadIdx.x; i < 1024; i += 256) s += partial[i];
    for (int off = 32; off; off >>= 1) s += __shfl_down(s, off, 64);
    __shared__ float w[4];
    int lane = threadIdx.x & 63, wv = threadIdx.x >> 6;
    if (lane == 0) w[wv] = s;
    __syncthreads();
    if (threadIdx.x == 0)
        loss[0] = 0.1f * (w[0] + w[1] + w[2] + w[3]) / (float)(NN * Dd);
}

// ---------------------------------------------------------------------------
extern "C" void kernel_launch(void* const* d_in, const int* in_sizes, int n_in,
                              void* d_out, int out_size, void* d_ws, size_t ws_size,
                              hipStream_t stream) {
    const int*   x    = (const int*)d_in[0];
    const float* te   = (const float*)d_in[1];
    const float* ew1  = (const float*)d_in[2];
    const float* eb1  = (const float*)d_in[3];
    const float* ew2  = (const float*)d_in[4];
    const float* eb2  = (const float*)d_in[5];
    const float* ew3  = (const float*)d_in[6];
    const float* eb3  = (const float*)d_in[7];
    const float* cb   = (const float*)d_in[8];
    const float* dw1  = (const float*)d_in[9];
    const float* db1  = (const float*)d_in[10];
    const float* dw2  = (const float*)d_in[11];
    const float* db2  = (const float*)d_in[12];
    const float* dw3  = (const float*)d_in[13];
    const float* db3  = (const float*)d_in[14];
    const float* outw = (const float*)d_in[15];
    const float* outb = (const float*)d_in[16];

    char* ws = (char*)d_ws;
    size_t off = 0;
    auto alloc = [&](size_t bytes) -> void* {
        void* p = ws + off;
        off = (off + bytes + 255) & ~(size_t)255;
        return p;
    };
    float* bufA   = (float*)alloc((size_t)NN * Ee * 4);          // emb
    float* bufB   = (float*)alloc((size_t)NN * Hh * 4);          // h1 (enc)
    float* bufC   = (float*)alloc((size_t)NN * Hh * 4);          // h2 (enc)
    float* bufZ   = (float*)alloc((size_t)NN * Dd * 4);          // z_e
    float* bufQ   = (float*)alloc((size_t)NN * Dd * 4);          // z_q (fp32)
    int*   codesi = (int*)alloc((size_t)NN * 4);
    float* part   = (float*)alloc(1024 * 4);
    float* wt_e1  = (float*)alloc((size_t)3 * Ee * Hh * 4);
    float* wt_e2  = (float*)alloc((size_t)3 * Hh * Hh * 4);
    float* wt_e3  = (float*)alloc((size_t)Hh * Dd * 4);
    // bf16x3 buffers (+1 guard row each)
    short* cb3    = (short*)alloc((size_t)Kc * 3 * Dd * 2);          // 512 x 192
    short* q3     = (short*)alloc((size_t)(NN + 1) * 3 * Dd * 2);    // (NN+1) x 192
    short* h1_3   = (short*)alloc((size_t)(NN + 1) * 3 * Hh * 2);    // (NN+1) x 768
    short* h2_3   = (short*)alloc((size_t)(NN + 1) * 3 * Hh * 2);    // (NN+1) x 768
    short* h3_3   = (short*)alloc((size_t)(NN + 1) * 3 * Ee * 2);    // (NN+1) x 384
    short* wd1_3  = (short*)alloc((size_t)Hh * 3 * Dd * 2);          // 256 x 192
    short* wd2_3  = (short*)alloc((size_t)Hh * 9 * Hh * 2);          // 256 x 2304
    short* wd3_3  = (short*)alloc((size_t)Ee * 3 * Hh * 2);          // 128 x 768
    short* wo3    = (short*)alloc((size_t)Vv * 3 * Ee * 2);          // 4096 x 384

    float* out       = (float*)d_out;
    float* out_loss  = out + (size_t)LOGITS;
    float* out_codes = out_loss + 1;

    auto tg = [](int n) { return dim3((n + 255) / 256); };
    // Encoder weights (fp32 transpose)
    transpose_w<<<tg(Hh * Ee * 3), 256, 0, stream>>>(ew1, wt_e1, Hh, Ee, 3);
    transpose_w<<<tg(Hh * Hh * 3), 256, 0, stream>>>(ew2, wt_e2, Hh, Hh, 3);
    transpose_w<<<tg(Dd * Hh),     256, 0, stream>>>(ew3, wt_e3, Dd, Hh, 1);
    // Decoder + vocab weights (bf16x3 split; k=1 weights are row-major (Cout,Cin))
    split3<false><<<tg(Hh * Dd),  256, 0, stream>>>(dw1, wd1_3, Dd);
    split3_w3<<<tg(Hh * Hh * 3),  256, 0, stream>>>(dw2, wd2_3, Hh, Hh);
    split3<false><<<tg(Ee * Hh),  256, 0, stream>>>(dw3, wd3_3, Hh);
    split3<false><<<tg(Vv * Ee),  256, 0, stream>>>(outw, wo3, Ee);
    split3<true><<<tg(Kc * Dd),   256, 0, stream>>>(cb, cb3, Dd);
    zero_guards<<<dim3(1), 256, 0, stream>>>(q3, h1_3, h2_3, h3_3);

    embed_kernel<<<dim3(NN * 32 / 256), 256, 0, stream>>>(x, (const float4*)te, (float4*)bufA);

    // Encoder (fp32 to keep VQ argmin exact — bf16x3 z_e error can flip codes)
    gemm_conv<3, true, 128, 128, 8, 8><<<dim3(NN / 128, Hh / 128), 256, 0, stream>>>(bufA, wt_e1, eb1, bufB, Ee, Hh);
    gemm_conv<3, true, 128, 128, 8, 8><<<dim3(NN / 128, Hh / 128), 256, 0, stream>>>(bufB, wt_e2, eb2, bufC, Hh, Hh);
    gemm_conv<1, false, 64, 64, 4, 4><<<dim3(NN / 64, 1), 256, 0, stream>>>(bufC, wt_e3, eb3, bufZ, Hh, Dd);

    // VQ
    vq_kernel<<<dim3(NN / 64), 256, 0, stream>>>(bufZ, cb, codesi, out_codes);
    gather_zq<<<dim3(NN * 16 / 256), 256, 0, stream>>>(codesi, (const float4*)cb, (float4*)bufQ);
    gather_q3<<<tg(NN * 24), 256, 0, stream>>>(codesi, (const float4*)cb3, (float4*)q3);
    commit_partial<<<dim3(1024), 256, 0, stream>>>(bufZ, bufQ, part);
    commit_final<<<dim3(1), 256, 0, stream>>>(part, out_loss);

    // Decoder (bf16x3 MFMA; each epilogue emits the next layer's operand)
    gemm_mfma<1, true, true><<<dim3((NN / 128) * (Hh / 128)), 256, 0, stream>>>(
        q3, wd1_3, db1, nullptr, h1_3, 3 * Dd, Hh);
    gemm_mfma<3, true, true><<<dim3((NN / 128) * (Hh / 128)), 256, 0, stream>>>(
        h1_3, wd2_3, db2, nullptr, h2_3, 3 * Hh, Hh);
    gemm_mfma<1, true, true><<<dim3((NN / 128) * (Ee / 128)), 256, 0, stream>>>(
        h2_3, wd3_3, db3, nullptr, h3_3, 3 * Hh, Ee);

    // Vocab projection -> logits (bf16x3 MFMA, fp32 out)
    gemm_mfma<1, false, false><<<dim3((NN / 128) * (Vv / 128)), 256, 0, stream>>>(
        h3_3, wo3, outb, out, nullptr, 3 * Ee, Vv);
}